// Round 6
// baseline (322.964 us; speedup 1.0000x reference)
//
#include <hip/hip_runtime.h>
#include <math.h>

// x = (16, 32, 65536) fp32. One block per row; row STREAMED through LDS in
// 16 chunks of 4096 (register-residency failed 4x: the allocator demotes
// >=64-float per-thread arrays to scratch regardless of launch bounds —
// rounds 2-5: 150-800 MB scratch traffic. The chunked-LDS structure from
// rounds 0/1 allocated cleanly: zero spill, zero bank conflicts).
//
// Three scans (minimum: two data-dependent row-wide thresholds):
//   S1: stats1 over residual(x)              (read x)
//   S2: stats2 over residual(y), y=apply1(x) recomputed on the fly (read x)
//   S3: out = apply2(y(x), th2)              (read x, write out)
// y is never materialized -> HBM floor 134 R + 134 W; S2/S3 re-reads of x
// are L2/L3 candidates. Single launch, no workspace, no cross-block deps.
#define LROW   65536
#define NROWS  512
#define NT     512              // 8 waves
#define NW     (NT / 64)
#define NCHK   16
#define CHUNK  4096
#define EPC    (CHUNK / NT)     // 8 elements per thread per chunk
#define HB     10               // staged halo (S3 needs x at +/-10)
#define NELEM  (CHUNK + 2 * HB) // 4116 logical floats in LDS

#define TREND_SCALING       0.6f
#define DETAIL_PRESERVATION 0.85f
#define SPIKE_THRESHOLD     3.5f
#define SPIKE_DAMPING       0.35f
#define EPSV                1e-6f

// LDS swizzle (round-0/1 proven, SQ_LDS_BANK_CONFLICT == 0): phys = i + i/16.
__device__ __forceinline__ int sw(int i) { return i + (i >> 4); }

// Deterministic block threshold from per-thread f64 partials:
// 64-lane butterfly -> NW wave partials -> fixed-order finalize by all.
__device__ __forceinline__ float block_thresh(double s, double q,
                                              double* __restrict__ wred,
                                              const int tid) {
#pragma unroll
    for (int off = 32; off > 0; off >>= 1) {
        s += __shfl_xor(s, off);
        q += __shfl_xor(q, off);
    }
    if ((tid & 63) == 0) {
        wred[tid >> 6] = s;
        wred[(tid >> 6) + NW] = q;
    }
    __syncthreads();
    double S = 0.0, Q = 0.0;
#pragma unroll
    for (int w = 0; w < NW; w++) { S += wred[w]; Q += wred[w + NW]; }
    const double N = (double)LROW;
    double var = (Q - S * S / N) / (N - 1.0);
    if (var < 0.0) var = 0.0;
    return fmaxf((float)sqrt(var), EPSV) * SPIKE_THRESHOLD;
}

// ---------------------------------------------------------------------------
__global__ __launch_bounds__(NT) void k_fused(const float* __restrict__ x,
                                              float* __restrict__ out,
                                              const float* __restrict__ k5,
                                              const float* __restrict__ k11) {
    __shared__ float buf[NELEM + (NELEM >> 4) + 4];
    __shared__ double wred[2 * NW];

    const int row = blockIdx.x;
    const int tid = threadIdx.x;
    const size_t rowBase = (size_t)row * LROW;
    const float w5 = k5[0];
    const float w11 = k11[0];
    const int E0 = tid * EPC;           // thread's element offset within chunk

    // ---- chunk load helpers (reg-staged prefetch, aligned float4 body +
    //      20 halo scalars with row-reflect) ----
    float4 r0, r1;   // body: float4s j4 = tid and tid+NT
    float hreg;      // one halo scalar for tid<20
#define LOAD_CHUNK(c)                                                         \
    {                                                                         \
        const float4* s4 = (const float4*)(x + rowBase + (c) * CHUNK);        \
        r0 = s4[tid];                                                         \
        r1 = s4[tid + NT];                                                    \
        if (tid < 2 * HB) {                                                   \
            int g = (tid < HB) ? ((c) * CHUNK - HB + tid)                     \
                               : ((c) * CHUNK + CHUNK + tid - HB);            \
            g = (g < 0) ? -g : (g >= LROW ? 2 * LROW - 2 - g : g);            \
            hreg = x[rowBase + g];                                            \
        }                                                                     \
    }
#define STORE_CHUNK()                                                         \
    {                                                                         \
        int l0 = tid * 4 + HB;                                                \
        buf[sw(l0)] = r0.x; buf[sw(l0 + 1)] = r0.y;                           \
        buf[sw(l0 + 2)] = r0.z; buf[sw(l0 + 3)] = r0.w;                       \
        int l1 = (tid + NT) * 4 + HB;                                         \
        buf[sw(l1)] = r1.x; buf[sw(l1 + 1)] = r1.y;                           \
        buf[sw(l1 + 2)] = r1.z; buf[sw(l1 + 3)] = r1.w;                       \
        if (tid < 2 * HB) {                                                   \
            int l = (tid < HB) ? tid : (CHUNK + HB + tid - HB);               \
            buf[sw(l)] = hreg;                                                \
        }                                                                     \
    }

    // ================= S1: stats over residual(x) =================
    double s = 0.0, q = 0.0;
    LOAD_CHUNK(0)
#pragma unroll 1
    for (int c = 0; c < NCHK; ++c) {
        __syncthreads();             // WAR: previous compute done with buf
        STORE_CHUNK()
        if (c < NCHK - 1) LOAD_CHUNK(c + 1)
        __syncthreads();             // LDS writes visible
        float v[EPC + 4];            // x[E0-2 .. E0+EPC+1]
#pragma unroll
        for (int m = 0; m < EPC + 4; m++) v[m] = buf[sw(E0 + (HB - 2) + m)];
#pragma unroll
        for (int k = 0; k < EPC; k++) {
            float lac = 0.f;
#pragma unroll
            for (int d = 0; d < 5; d++) lac = fmaf(v[k + d], w5, lac);
            float r = v[k + 2] - lac;
            s += (double)r;
            q += (double)r * (double)r;
        }
    }
    const float th1 = block_thresh(s, q, wred, tid);

    // ================= S2: stats over residual(y), y = apply1(x) ==========
    s = 0.0; q = 0.0;
    LOAD_CHUNK(0)
#pragma unroll 1
    for (int c = 0; c < NCHK; ++c) {
        __syncthreads();
        STORE_CHUNK()
        if (c < NCHK - 1) LOAD_CHUNK(c + 1)
        __syncthreads();
        float xw[EPC + 14];          // x[E0-7 .. E0+EPC+6]
#pragma unroll
        for (int m = 0; m < EPC + 14; m++) xw[m] = buf[sw(E0 + (HB - 7) + m)];
        float y[EPC + 4];            // y at positions E0-2 .. E0+EPC+1
#pragma unroll
        for (int j = 0; j < EPC + 4; j++) {
            float lac = 0.f, tac = 0.f;
#pragma unroll
            for (int d = 0; d < 5; d++) lac = fmaf(xw[j + 3 + d], w5, lac);
#pragma unroll
            for (int d = 0; d < 11; d++) tac = fmaf(xw[j + d], w11, tac);
            float cur = xw[j + 5];
            float r = cur - lac;
            r = (fabsf(r) > th1) ? r * SPIKE_DAMPING : r;
            float comb = (1.0f - TREND_SCALING) * lac + TREND_SCALING * tac;
            y[j] = comb + DETAIL_PRESERVATION * r;
        }
#pragma unroll
        for (int k = 0; k < EPC; k++) {
            float lac = 0.f;
#pragma unroll
            for (int d = 0; d < 5; d++) lac = fmaf(y[k + d], w5, lac);
            float r = y[k + 2] - lac;
            s += (double)r;
            q += (double)r * (double)r;
        }
    }
    const float th2 = block_thresh(s, q, wred, tid);

    // ================= S3: out = apply2(y(x), th2) =================
    LOAD_CHUNK(0)
#pragma unroll 1
    for (int c = 0; c < NCHK; ++c) {
        __syncthreads();
        STORE_CHUNK()
        if (c < NCHK - 1) LOAD_CHUNK(c + 1)
        __syncthreads();
        float xw[EPC + 20];          // x[E0-10 .. E0+EPC+9]
#pragma unroll
        for (int m = 0; m < EPC + 20; m++) xw[m] = buf[sw(E0 + m)];
        float y[EPC + 10];           // y at positions E0-5 .. E0+EPC+4
#pragma unroll
        for (int j = 0; j < EPC + 10; j++) {
            float lac = 0.f, tac = 0.f;
#pragma unroll
            for (int d = 0; d < 5; d++) lac = fmaf(xw[j + 3 + d], w5, lac);
#pragma unroll
            for (int d = 0; d < 11; d++) tac = fmaf(xw[j + d], w11, tac);
            float cur = xw[j + 5];
            float r = cur - lac;
            r = (fabsf(r) > th1) ? r * SPIKE_DAMPING : r;
            float comb = (1.0f - TREND_SCALING) * lac + TREND_SCALING * tac;
            y[j] = comb + DETAIL_PRESERVATION * r;
        }
        float o[EPC];
#pragma unroll
        for (int k = 0; k < EPC; k++) {
            float lac = 0.f, tac = 0.f;
#pragma unroll
            for (int d = 0; d < 5; d++) lac = fmaf(y[k + 3 + d], w5, lac);
#pragma unroll
            for (int d = 0; d < 11; d++) tac = fmaf(y[k + d], w11, tac);
            float cur = y[k + 5];
            float r = cur - lac;
            r = (fabsf(r) > th2) ? r * SPIKE_DAMPING : r;
            float comb = (1.0f - TREND_SCALING) * lac + TREND_SCALING * tac;
            o[k] = comb + DETAIL_PRESERVATION * r;
        }
        float4* d4 = (float4*)(out + rowBase + c * CHUNK + E0);
        d4[0] = make_float4(o[0], o[1], o[2], o[3]);
        d4[1] = make_float4(o[4], o[5], o[6], o[7]);
    }
#undef LOAD_CHUNK
#undef STORE_CHUNK
}

extern "C" void kernel_launch(void* const* d_in, const int* in_sizes, int n_in,
                              void* d_out, int out_size, void* d_ws, size_t ws_size,
                              hipStream_t stream) {
    (void)in_sizes; (void)n_in; (void)out_size; (void)d_ws; (void)ws_size;
    const float* x = (const float*)d_in[0];
    const float* k5 = (const float*)d_in[1];
    const float* k11 = (const float*)d_in[2];
    float* out = (float*)d_out;

    hipLaunchKernelGGL(k_fused, dim3(NROWS), dim3(NT), 0, stream, x, out, k5, k11);
}